// Round 9
// baseline (513.358 us; speedup 1.0000x reference)
//
#include <hip/hip_runtime.h>
#include <hip/hip_bf16.h>
#include <stdint.h>

// FPNAttentionV2 v11: v10 A-share fusion with THIN BLOCKS (latency-bound fix).
//   fused_gemm: 64x256 tiles, 32KB LDS -> 4 blocks/CU (16 waves/CU, was 8).
//     blocks 0..127:   kdown, full N=256 per block (ntile merged -> halves tap re-stage)
//     blocks 128..639: x1 group (64-row tile staged once -> q1, ks1, v1)
//     blocks 640..767: x2 group (64-row tile staged once -> q2, ks2, v2, kup)
//   Keeps: XOR-swizzled LDS, swapped-operand MFMA (f32x4 stores), fetch dedup.

typedef __attribute__((ext_vector_type(8))) __bf16 bf16x8;
typedef __attribute__((ext_vector_type(4))) float f32x4;
typedef __attribute__((ext_vector_type(8))) unsigned short u16x8;

typedef const __attribute__((address_space(1))) uint32_t* gptr_t;
typedef __attribute__((address_space(3))) uint32_t* lptr_t;

__device__ __forceinline__ void cp16(void* lds, const void* g) {
  // async global->LDS, 16B/lane; LDS dest wave-uniform (HW adds lane*16)
  gptr_t gp = reinterpret_cast<gptr_t>(reinterpret_cast<uintptr_t>(g));
  lptr_t lp = reinterpret_cast<lptr_t>(
      static_cast<uint32_t>(reinterpret_cast<uintptr_t>(lds)));
  __builtin_amdgcn_global_load_lds(gp, lp, 16, 0, 0);
}

// ---------------- prep + transpose merged (unchanged) ----------------
struct WArgs {
  const float* w1[7];
  const float* kdw;  // [256][256][3][3]
};

__global__ void prep_transpose(WArgs a, const float* __restrict__ x1,
                               const float* __restrict__ x2,
                               uint16_t* __restrict__ wf,
                               uint16_t* __restrict__ x1p,
                               uint16_t* __restrict__ x2b) {
  __shared__ float tile[64][65];
  const int bx = blockIdx.x;
  const int tid = threadIdx.x;
  if (bx < 512) {
    // frag-major per matrix (65536 elems): [jg(16)][kc(8)][lane(64)][e(8)]
    const int idx = bx * 256 + tid;  // 131072
    const int mat = idx >> 13;
    const int g = idx & 8191;
    const int jg = g >> 9;
    const int kc = (g >> 6) & 7;
    const int lane = g & 63;
    const int o = jg * 16 + (lane & 15);
    const int k0 = kc * 32 + (lane >> 4) * 8;
    float f[8];
    if (mat < 7) {
      const float* w = a.w1[mat];
      const float4 v0 = *(const float4*)(w + o * 256 + k0);
      const float4 v1 = *(const float4*)(w + o * 256 + k0 + 4);
      f[0] = v0.x; f[1] = v0.y; f[2] = v0.z; f[3] = v0.w;
      f[4] = v1.x; f[5] = v1.y; f[6] = v1.z; f[7] = v1.w;
    } else {
      const int tap = mat - 7;
#pragma unroll
      for (int e = 0; e < 8; e++)
        f[e] = a.kdw[(long)o * 2304 + (long)(k0 + e) * 9 + tap];
    }
    u16x8 u;
#pragma unroll
    for (int e = 0; e < 8; e++) {
      __hip_bfloat16 hb = __float2bfloat16(f[e]);
      u[e] = *reinterpret_cast<uint16_t*>(&hb);
    }
    *(u16x8*)(wf + (long)idx * 8) = u;
    return;
  }
  if (bx < 641) {
    // zero the pad ring of x1p [2][130][130][256]; 33024 16B-chunks
    const int c = (bx - 512) * 256 + tid;
    const int b = (c >= 16512) ? 1 : 0;
    const int cc = c - b * 16512;
    int h, w, g8;
    if (cc < 4160) {
      h = 0; w = cc >> 5; g8 = cc & 31;
    } else if (cc < 8320) {
      const int s = cc - 4160; h = 129; w = s >> 5; g8 = s & 31;
    } else if (cc < 12416) {
      const int s = cc - 8320; h = 1 + (s >> 5); w = 0; g8 = s & 31;
    } else {
      const int s = cc - 12416; h = 1 + (s >> 5); w = 129; g8 = s & 31;
    }
    u16x8 z = {};
    *(u16x8*)(x1p + (((long)(b * 130 + h)) * 130 + w) * 256 + g8 * 8) = z;
    return;
  }
  // ---- transpose: NCHW f32 -> NHWC bf16 ----
  const int t = bx - 641;  // 0..2559
  const float* src;
  uint16_t* dst;
  int H, W, pad, b, h, bxx, by;
  if (t < 2048) {
    src = x1; dst = x1p; H = 128; W = 128; pad = 1;
    bxx = t & 1; by = (t >> 1) & 3;
    const int z = t >> 3; b = z >> 7; h = z & 127;
  } else {
    const int t2 = t - 2048;  // 0..511
    src = x2; dst = x2b; H = 64; W = 64; pad = 0;
    bxx = 0; by = t2 & 3;
    const int z = t2 >> 2;  // 0..127
    b = z >> 6; h = z & 63;
  }
  const int wt = bxx * 64;
  const int ct = by * 64;
  const long cs = (long)H * W;
  const float* s = src + ((long)(b * 256 + ct) * H + h) * W + wt;
  const int rw = tid >> 4;
  const int rf = tid & 15;
#pragma unroll
  for (int p = 0; p < 4; p++) {
    const int cl = p * 16 + rw;
    const float4 v = *(const float4*)(s + (long)cl * cs + rf * 4);
    tile[cl][rf * 4 + 0] = v.x;
    tile[cl][rf * 4 + 1] = v.y;
    tile[cl][rf * 4 + 2] = v.z;
    tile[cl][rf * 4 + 3] = v.w;
  }
  __syncthreads();
  const int wl0 = tid >> 3;
  const int cg = tid & 7;
  const int Wp = W + 2 * pad;
  const long rowb = ((long)(b * (H + 2 * pad) + h + pad)) * Wp + pad + wt;
#pragma unroll
  for (int p = 0; p < 2; p++) {
    const int wl = p * 32 + wl0;
    u16x8 u;
#pragma unroll
    for (int k = 0; k < 8; k++) {
      __hip_bfloat16 hb = __float2bfloat16(tile[cg * 8 + k][wl]);
      u[k] = *reinterpret_cast<uint16_t*>(&hb);
    }
    *(u16x8*)(dst + (rowb + wl) * 256 + ct + cg * 8) = u;
  }
}

// ---------------- fused GEMM (A-share, thin 64x256 blocks) ----------------
struct GArgs {
  const uint16_t* x1p;
  const uint16_t* x2b;
  const uint16_t* wf;  // 16 matrices x 65536, frag-major
  const float* b_q1; const float* b_q2; const float* b_ks1; const float* b_ks2;
  const float* b_kup; const float* b_v1; const float* b_v2; const float* b_kd;
  float* o_q1; float* o_q2; float* o_ks1; float* o_ks2;
  float* o_kup; float* o_v1; float* o_v2; float* o_kd;
};

// block 256 = 4 waves (2x2). Tile 64 rows x 256 N, full K=256 in 32KB LDS
// ([kc(8)][row(64)][32 elems]). 4 blocks/CU (16 waves/CU).
// blocks 0..127:   kdown 3x3s2, full N=256, 9 taps staged into the same buffer.
// blocks 128..639: x1 group -> q1, ks1, v1.
// blocks 640..767: x2 group -> q2, ks2, v2, kup(upsample).
// LDS rows 32 elems (4 x 16B slots), XOR-swizzled sw(row)=(row>>1)&3; stage keeps
// LDS dest linear, pre-swizzles GLOBAL k-chunk (ksel); ds_read applies same XOR (qsw).
// MFMA operands swapped: mfma(W_frag, X_frag) -> D: lane&15 = spatial, q*4+reg = 4
// consecutive channels -> f32x4 stores.
__global__ __launch_bounds__(256, 4) void fused_gemm(GArgs a) {
  const int bid = blockIdx.x;

  __shared__ __align__(16) uint16_t lA[16384];  // 32KB

  const int tid = threadIdx.x;
  const int lane = tid & 63;
  const int wave = tid >> 6;
  const int wr = wave & 1;
  const int wc = wave >> 1;
  const int q = lane >> 4;
  const int l15 = lane & 15;
  const int ksel = ((lane & 3) ^ ((lane >> 3) & 3)) * 8;  // stage-side swizzle
  const int qsw = (q ^ ((l15 >> 1) & 3)) * 8;             // read-side swizzle

  if (bid < 128) {
    // ---- kdown: 64 rows x full N=256, mtile = bid ----
    const int mtile = bid;
    const int row = mtile * 64 + wave * 16 + (lane >> 2);
    // row = b*4096 + oh*64 + ow -> padded (b, 2oh, 2ow)
    const long p =
        ((long)((row >> 12) * 130 + 2 * ((row >> 6) & 63))) * 130 + 2 * (row & 63);
    const uint16_t* rowA = a.x1p + p * 256 + ksel;

    f32x4 acc[2][8] = {};
    for (int tap = 0; tap < 9; tap++) {
      const int kh = tap / 3;
      const int kw = tap - kh * 3;
      const long aoff = (long)(kh * 130 + kw) * 256;
      const uint16_t* wfp = a.wf + (long)(7 + tap) * 65536;
      if (tap) __syncthreads();
#pragma unroll
      for (int kap = 0; kap < 8; kap++)
        cp16(lA + (kap * 256 + wave * 64) * 8, rowA + aoff + kap * 32);
      __syncthreads();
#pragma unroll
      for (int kc = 0; kc < 8; kc++) {
        bf16x8 av[2];
#pragma unroll
        for (int i = 0; i < 2; i++)
          av[i] = *(const bf16x8*)(lA + (kc * 64 + wr * 32 + i * 16 + l15) * 32 + qsw);
#pragma unroll
        for (int j = 0; j < 8; j++) {
          const bf16x8 bv = *(const bf16x8*)(
              wfp + ((long)((wc * 8 + j) * 8 + kc) * 64 + lane) * 8);
#pragma unroll
          for (int i = 0; i < 2; i++)
            acc[i][j] = __builtin_amdgcn_mfma_f32_16x16x32_bf16(bv, av[i],
                                                                acc[i][j], 0, 0, 0);
        }
      }
    }
    // D (swapped): lane&15 = spatial, q*4+reg = channel
    const int nb2 = wc * 128 + q * 4;
    const int mb2 = mtile * 64 + wr * 32 + l15;
#pragma unroll
    for (int j = 0; j < 8; j++) {
      const int n = nb2 + j * 16;
      const f32x4 bq = *(const f32x4*)(a.b_kd + n);
#pragma unroll
      for (int i = 0; i < 2; i++) {
        const int m = mb2 + i * 16;
        *(f32x4*)(a.o_kd + (long)m * 256 + n) = acc[i][j] + bq;
      }
    }
    return;
  }

  // ---- multi-job 1x1 groups, 64-row tiles ----
  const int x1grp = (bid < 640) ? 1 : 0;
  const int mtile = x1grp ? (bid - 128) : (bid - 640);
  const uint16_t* A = x1grp ? a.x1p : a.x2b;
  const int njobs = x1grp ? 3 : 4;

  // stage 32KB once: [kc(8)][row(64)][4 swizzled 16B slots]
  {
    const int m = mtile * 64 + wave * 16 + (lane >> 2);
    long p;
    if (x1grp) {
      p = ((long)((m >> 14) * 130 + ((m >> 7) & 127) + 1)) * 130 + (m & 127) + 1;
    } else {
      p = m;
    }
    const uint16_t* rowA = A + p * 256 + ksel;
#pragma unroll
    for (int kap = 0; kap < 8; kap++)
      cp16(lA + (kap * 256 + wave * 64) * 8, rowA + kap * 32);
  }
  __syncthreads();

  // jobs consume the same LDS tile; no barriers between jobs.
#pragma unroll 1
  for (int jj = 0; jj < njobs; jj++) {
    int mat;
    const float* bias;
    float* outp;
    int ups = 0;
    if (x1grp) {
      if (jj == 0)      { mat = 0; bias = a.b_q1;  outp = a.o_q1;  }
      else if (jj == 1) { mat = 2; bias = a.b_ks1; outp = a.o_ks1; }
      else              { mat = 5; bias = a.b_v1;  outp = a.o_v1;  }
    } else {
      if (jj == 0)      { mat = 1; bias = a.b_q2;  outp = a.o_q2;  }
      else if (jj == 1) { mat = 3; bias = a.b_ks2; outp = a.o_ks2; }
      else if (jj == 2) { mat = 6; bias = a.b_v2;  outp = a.o_v2;  }
      else              { mat = 4; bias = a.b_kup; outp = a.o_kup; ups = 1; }
    }
    const uint16_t* Wf = a.wf + (long)mat * 65536;

    f32x4 acc[2][8] = {};
#pragma unroll
    for (int kc = 0; kc < 8; kc++) {
      bf16x8 av[2];
#pragma unroll
      for (int i = 0; i < 2; i++)
        av[i] = *(const bf16x8*)(lA + (kc * 64 + wr * 32 + i * 16 + l15) * 32 + qsw);
#pragma unroll
      for (int j = 0; j < 8; j++) {
        const bf16x8 bv =
            *(const bf16x8*)(Wf + ((long)((wc * 8 + j) * 8 + kc) * 64 + lane) * 8);
#pragma unroll
        for (int i = 0; i < 2; i++)
          acc[i][j] = __builtin_amdgcn_mfma_f32_16x16x32_bf16(bv, av[i],
                                                              acc[i][j], 0, 0, 0);
      }
    }

    // epilogue (swapped D): lane&15 = spatial row, q*4+reg = 4 consecutive channels
    const int nb2 = wc * 128 + q * 4;
    const int mb2 = mtile * 64 + wr * 32 + l15;
    if (ups) {
#pragma unroll
      for (int j = 0; j < 8; j++) {
        const int n = nb2 + j * 16;
        const f32x4 bq = *(const f32x4*)(bias + n);
#pragma unroll
        for (int i = 0; i < 2; i++) {
          const int m = mb2 + i * 16;  // b*4096 + h2*64 + w2
          const int b = m >> 12;
          const int h2 = (m >> 6) & 63;
          const int w2 = m & 63;
          const f32x4 v = acc[i][j] + bq;
          float* o = outp + ((long)(b * 128 + 2 * h2) * 128 + 2 * w2) * 256 + n;
          *(f32x4*)(o) = v;
          *(f32x4*)(o + 256) = v;
          *(f32x4*)(o + 32768) = v;
          *(f32x4*)(o + 32768 + 256) = v;
        }
      }
    } else {
#pragma unroll
      for (int j = 0; j < 8; j++) {
        const int n = nb2 + j * 16;
        const f32x4 bq = *(const f32x4*)(bias + n);
#pragma unroll
        for (int i = 0; i < 2; i++) {
          const int m = mb2 + i * 16;
          *(f32x4*)(outp + (long)m * 256 + n) = acc[i][j] + bq;
        }
      }
    }
  }
}

extern "C" void kernel_launch(void* const* d_in, const int* in_sizes, int n_in,
                              void* d_out, int out_size, void* d_ws,
                              size_t ws_size, hipStream_t stream) {
  (void)in_sizes; (void)n_in; (void)out_size; (void)ws_size;
  const float* x1 = (const float*)d_in[0];
  const float* x2 = (const float*)d_in[1];
  float* out = (float*)d_out;

  uint16_t* x1p = (uint16_t*)d_ws;  // [2][130][130][256] = 8,652,800
  uint16_t* x2b = x1p + 8652800;    // [2][64][64][256]   = 2,097,152
  uint16_t* wf = x2b + 2097152;     // 16 x 65536 frag-major

  WArgs wa;
  wa.w1[0] = (const float*)d_in[2];   // q1_w
  wa.w1[1] = (const float*)d_in[4];   // q2_w
  wa.w1[2] = (const float*)d_in[6];   // ks1_w
  wa.w1[3] = (const float*)d_in[8];   // ks2_w
  wa.w1[4] = (const float*)d_in[10];  // kup_w
  wa.w1[5] = (const float*)d_in[12];  // v1_w
  wa.w1[6] = (const float*)d_in[14];  // v2_w
  wa.kdw = (const float*)d_in[16];    // kdown_w
  prep_transpose<<<3201, 256, 0, stream>>>(wa, x1, x2, wf, x1p, x2b);

  // d_out float offsets (tuple order):
  // q1:0 q2:8388608 k_up:10485760 k_self1:18874368 k_self2:27262976
  // k_down:29360128 v1:31457280 v2:39845888
  GArgs ga;
  ga.x1p = x1p; ga.x2b = x2b; ga.wf = wf;
  ga.b_q1  = (const float*)d_in[3];
  ga.b_q2  = (const float*)d_in[5];
  ga.b_ks1 = (const float*)d_in[7];
  ga.b_ks2 = (const float*)d_in[9];
  ga.b_kup = (const float*)d_in[11];
  ga.b_v1  = (const float*)d_in[13];
  ga.b_v2  = (const float*)d_in[15];
  ga.b_kd  = (const float*)d_in[17];
  ga.o_q1  = out + 0L;
  ga.o_q2  = out + 8388608L;
  ga.o_kup = out + 10485760L;
  ga.o_ks1 = out + 18874368L;
  ga.o_ks2 = out + 27262976L;
  ga.o_kd  = out + 29360128L;
  ga.o_v1  = out + 31457280L;
  ga.o_v2  = out + 39845888L;
  fused_gemm<<<768, 256, 0, stream>>>(ga);
}

// Round 15
// 291.842 us; speedup vs baseline: 1.7590x; 1.7590x over previous
//
#include <hip/hip_runtime.h>
#include <hip/hip_bf16.h>
#include <stdint.h>

// FPNAttentionV2 v12 (5th resubmit — rounds 10-14 all infra failures, never ran).
// v8 structure (best-measured family: 1280 uniform blocks, 128x256 1x1 tiles /
// 64x128 kdown, XOR-swizzled LDS, swapped-operand MFMA with f32x4 epilogue)
// + NON-TEMPORAL output stores (outputs are write-once; keep them out of L2 so
// x1p/x2b/weights stay resident for the other blocks).
// v9-v11 A-share dedup REJECTED: traffic was never binding; grid width x uniform
// block duration is (v6=291 < v10=367 < v11=513).

typedef __attribute__((ext_vector_type(8))) __bf16 bf16x8;
typedef __attribute__((ext_vector_type(4))) float f32x4;
typedef __attribute__((ext_vector_type(8))) unsigned short u16x8;

typedef const __attribute__((address_space(1))) uint32_t* gptr_t;
typedef __attribute__((address_space(3))) uint32_t* lptr_t;

__device__ __forceinline__ void cp16(void* lds, const void* g) {
  // async global->LDS, 16B/lane; LDS dest wave-uniform (HW adds lane*16)
  gptr_t gp = reinterpret_cast<gptr_t>(reinterpret_cast<uintptr_t>(g));
  lptr_t lp = reinterpret_cast<lptr_t>(
      static_cast<uint32_t>(reinterpret_cast<uintptr_t>(lds)));
  __builtin_amdgcn_global_load_lds(gp, lp, 16, 0, 0);
}

__device__ __forceinline__ void ntst(float* p, f32x4 v) {
  __builtin_nontemporal_store(v, (f32x4*)p);
}

// ---------------- prep + transpose merged ----------------
// blocks 0..511:    weights f32 -> bf16 frag-major
// blocks 512..640:  zero x1p pad ring
// blocks 641..2688: x1 NCHW f32 -> NHWC bf16 (padded), 2048 blocks
// blocks 2689..3200: x2 NCHW f32 -> NHWC bf16, 512 blocks
struct WArgs {
  const float* w1[7];
  const float* kdw;  // [256][256][3][3]
};

__global__ void prep_transpose(WArgs a, const float* __restrict__ x1,
                               const float* __restrict__ x2,
                               uint16_t* __restrict__ wf,
                               uint16_t* __restrict__ x1p,
                               uint16_t* __restrict__ x2b) {
  __shared__ float tile[64][65];
  const int bx = blockIdx.x;
  const int tid = threadIdx.x;
  if (bx < 512) {
    // frag-major per matrix (65536 elems): [jg(16)][kc(8)][lane(64)][e(8)]
    //   o = jg*16 + (lane&15), k = kc*32 + (lane>>4)*8 + e
    const int idx = bx * 256 + tid;  // 131072
    const int mat = idx >> 13;
    const int g = idx & 8191;
    const int jg = g >> 9;
    const int kc = (g >> 6) & 7;
    const int lane = g & 63;
    const int o = jg * 16 + (lane & 15);
    const int k0 = kc * 32 + (lane >> 4) * 8;
    float f[8];
    if (mat < 7) {
      const float* w = a.w1[mat];
      const float4 v0 = *(const float4*)(w + o * 256 + k0);
      const float4 v1 = *(const float4*)(w + o * 256 + k0 + 4);
      f[0] = v0.x; f[1] = v0.y; f[2] = v0.z; f[3] = v0.w;
      f[4] = v1.x; f[5] = v1.y; f[6] = v1.z; f[7] = v1.w;
    } else {
      const int tap = mat - 7;
#pragma unroll
      for (int e = 0; e < 8; e++)
        f[e] = a.kdw[(long)o * 2304 + (long)(k0 + e) * 9 + tap];
    }
    u16x8 u;
#pragma unroll
    for (int e = 0; e < 8; e++) {
      __hip_bfloat16 hb = __float2bfloat16(f[e]);
      u[e] = *reinterpret_cast<uint16_t*>(&hb);
    }
    *(u16x8*)(wf + (long)idx * 8) = u;
    return;
  }
  if (bx < 641) {
    // zero the pad ring of x1p [2][130][130][256]; 33024 16B-chunks
    const int c = (bx - 512) * 256 + tid;
    const int b = (c >= 16512) ? 1 : 0;
    const int cc = c - b * 16512;
    int h, w, g8;
    if (cc < 4160) {
      h = 0; w = cc >> 5; g8 = cc & 31;
    } else if (cc < 8320) {
      const int s = cc - 4160; h = 129; w = s >> 5; g8 = s & 31;
    } else if (cc < 12416) {
      const int s = cc - 8320; h = 1 + (s >> 5); w = 0; g8 = s & 31;
    } else {
      const int s = cc - 12416; h = 1 + (s >> 5); w = 129; g8 = s & 31;
    }
    u16x8 z = {};
    *(u16x8*)(x1p + (((long)(b * 130 + h)) * 130 + w) * 256 + g8 * 8) = z;
    return;
  }
  // ---- transpose: NCHW f32 -> NHWC bf16 ----
  const int t = bx - 641;  // 0..2559
  const float* src;
  uint16_t* dst;
  int H, W, pad, b, h, bxx, by;
  if (t < 2048) {
    src = x1; dst = x1p; H = 128; W = 128; pad = 1;
    bxx = t & 1; by = (t >> 1) & 3;
    const int z = t >> 3; b = z >> 7; h = z & 127;
  } else {
    const int t2 = t - 2048;  // 0..511
    src = x2; dst = x2b; H = 64; W = 64; pad = 0;
    bxx = 0; by = t2 & 3;
    const int z = t2 >> 2;  // 0..127
    b = z >> 6; h = z & 63;
  }
  const int wt = bxx * 64;
  const int ct = by * 64;
  const long cs = (long)H * W;
  const float* s = src + ((long)(b * 256 + ct) * H + h) * W + wt;
  const int rw = tid >> 4;
  const int rf = tid & 15;
#pragma unroll
  for (int p = 0; p < 4; p++) {
    const int cl = p * 16 + rw;
    const float4 v = *(const float4*)(s + (long)cl * cs + rf * 4);
    tile[cl][rf * 4 + 0] = v.x;
    tile[cl][rf * 4 + 1] = v.y;
    tile[cl][rf * 4 + 2] = v.z;
    tile[cl][rf * 4 + 3] = v.w;
  }
  __syncthreads();
  const int wl0 = tid >> 3;
  const int cg = tid & 7;
  const int Wp = W + 2 * pad;
  const long rowb = ((long)(b * (H + 2 * pad) + h + pad)) * Wp + pad + wt;
#pragma unroll
  for (int p = 0; p < 2; p++) {
    const int wl = p * 32 + wl0;
    u16x8 u;
#pragma unroll
    for (int k = 0; k < 8; k++) {
      __hip_bfloat16 hb = __float2bfloat16(tile[cg * 8 + k][wl]);
      u[k] = *reinterpret_cast<uint16_t*>(&hb);
    }
    *(u16x8*)(dst + (rowb + wl) * 256 + ct + cg * 8) = u;
  }
}

// ---------------- fused GEMM ----------------
struct Job {
  const uint16_t* A;
  const uint16_t* Wf;
  const float* bias;
  float* out;
  int start;  // first flat block id
  int mode;   // 0: x1 1x1, 1: x2 1x1, 2: x2 + 2x upsample, 3: kdown 3x3s2
};
struct JobArgs {
  Job j[8];
};

// block 256 = 4 waves (2x2). Modes 0-2: tile 128x256, full K=256 in LDS (64KB), one
// barrier pair. Mode 3: tile 64x128, 9 taps (K=2304), 32KB stage per tap.
// LDS rows 32 elems (4 x 16B slots), XOR-swizzled sw(row)=(row>>1)&3; stage keeps
// LDS dest linear, pre-swizzles GLOBAL k-chunk (ksel); ds_read applies same XOR (qsw).
// MFMA operands swapped: mfma(W_frag, X_frag) -> D: lane&15 = spatial, q*4+reg = 4
// consecutive channels -> f32x4 NON-TEMPORAL stores (write-once outputs bypass L2).
__global__ __launch_bounds__(256, 2) void fused_gemm(JobArgs args) {
  int jid = 0;
#pragma unroll
  for (int t = 1; t < 8; t++)
    if ((int)blockIdx.x >= args.j[t].start) jid = t;
  const Job jb = args.j[jid];
  const int bid = blockIdx.x - jb.start;
  const int mode = jb.mode;

  __shared__ __align__(16) uint16_t lA[32768];  // 64KB

  const int tid = threadIdx.x;
  const int lane = tid & 63;
  const int wave = tid >> 6;
  const int wr = wave & 1;
  const int wc = wave >> 1;
  const int q = lane >> 4;
  const int l15 = lane & 15;
  const int ksel = ((lane & 3) ^ ((lane >> 3) & 3)) * 8;  // stage-side swizzle
  const int qsw = (q ^ ((l15 >> 1) & 3)) * 8;             // read-side swizzle

  if (mode == 3) {
    // ---- kdown: 64x128 tile, mtile = bid>>1, ntile = bid&1 ----
    const int mtile = bid >> 1;
    const int ntile = bid & 1;
    const int row = mtile * 64 + wave * 16 + (lane >> 2);
    // row = b*4096 + oh*64 + ow -> padded (b, 2oh, 2ow)
    const long p =
        ((long)((row >> 12) * 130 + 2 * ((row >> 6) & 63))) * 130 + 2 * (row & 63);
    const uint16_t* rowA = jb.A + p * 256 + ksel;

    f32x4 acc[2][4] = {};
    for (int tap = 0; tap < 9; tap++) {
      const int kh = tap / 3;
      const int kw = tap - kh * 3;
      const long aoff = (long)(kh * 130 + kw) * 256;
      const uint16_t* wfp = jb.Wf + (long)tap * 65536;
      if (tap) __syncthreads();
#pragma unroll
      for (int kap = 0; kap < 8; kap++)
        cp16(lA + (kap * 256 + wave * 64) * 8, rowA + aoff + kap * 32);
      __syncthreads();
#pragma unroll
      for (int kc = 0; kc < 8; kc++) {
        bf16x8 av[2];
#pragma unroll
        for (int i = 0; i < 2; i++)
          av[i] = *(const bf16x8*)(lA + (kc * 64 + wr * 32 + i * 16 + l15) * 32 + qsw);
#pragma unroll
        for (int j = 0; j < 4; j++) {
          const bf16x8 bv = *(const bf16x8*)(
              wfp + ((long)((ntile * 8 + wc * 4 + j) * 8 + kc) * 64 + lane) * 8);
#pragma unroll
          for (int i = 0; i < 2; i++)
            acc[i][j] = __builtin_amdgcn_mfma_f32_16x16x32_bf16(bv, av[i],
                                                                acc[i][j], 0, 0, 0);
        }
      }
    }
    // D (swapped): lane&15 = spatial, q*4+reg = channel
    const int nb2 = ntile * 128 + wc * 64 + q * 4;
    const int mb2 = mtile * 64 + wr * 32 + l15;
#pragma unroll
    for (int j = 0; j < 4; j++) {
      const int n = nb2 + j * 16;
      const f32x4 bq = *(const f32x4*)(jb.bias + n);
#pragma unroll
      for (int i = 0; i < 2; i++) {
        const int m = mb2 + i * 16;
        ntst(jb.out + (long)m * 256 + n, acc[i][j] + bq);
      }
    }
    return;
  }

  // ---- 1x1 convs: tile 128x256, full K staged once ----
  const int mtile = bid;
  const uint16_t* rowA[2];
  {
    const int rbase = wave * 16 + (lane >> 2);
#pragma unroll
    for (int rh = 0; rh < 2; rh++) {
      const int m = mtile * 128 + rh * 64 + rbase;
      long p;
      if (mode == 0) {
        p = ((long)((m >> 14) * 130 + ((m >> 7) & 127) + 1)) * 130 + (m & 127) + 1;
      } else {
        p = m;
      }
      rowA[rh] = jb.A + p * 256 + ksel;
    }
  }

  // stage 64KB: [kc(8)][row(128)][4 swizzled 16B slots]
#pragma unroll
  for (int kap = 0; kap < 16; kap++)
    cp16(lA + (kap * 256 + wave * 64) * 8, rowA[kap & 1] + (kap >> 1) * 32);
  __syncthreads();

  f32x4 acc[4][8] = {};
#pragma unroll
  for (int kc = 0; kc < 8; kc++) {
    bf16x8 av[4];
#pragma unroll
    for (int i = 0; i < 4; i++)
      av[i] = *(const bf16x8*)(lA + (kc * 128 + wr * 64 + i * 16 + l15) * 32 + qsw);
#pragma unroll
    for (int j = 0; j < 8; j++) {
      const bf16x8 bv =
          *(const bf16x8*)(jb.Wf + ((long)((wc * 8 + j) * 8 + kc) * 64 + lane) * 8);
#pragma unroll
      for (int i = 0; i < 4; i++)
        acc[i][j] = __builtin_amdgcn_mfma_f32_16x16x32_bf16(bv, av[i],
                                                            acc[i][j], 0, 0, 0);
    }
  }

  // epilogue (swapped D): lane&15 = spatial row, q*4+reg = 4 consecutive channels
  const int nb2 = wc * 128 + q * 4;
  const int mb2 = mtile * 128 + wr * 64 + l15;
  if (mode == 2) {
#pragma unroll
    for (int j = 0; j < 8; j++) {
      const int n = nb2 + j * 16;
      const f32x4 bq = *(const f32x4*)(jb.bias + n);
#pragma unroll
      for (int i = 0; i < 4; i++) {
        const int m = mb2 + i * 16;  // b*4096 + h2*64 + w2
        const int b = m >> 12;
        const int h2 = (m >> 6) & 63;
        const int w2 = m & 63;
        const f32x4 v = acc[i][j] + bq;
        float* o = jb.out + ((long)(b * 128 + 2 * h2) * 128 + 2 * w2) * 256 + n;
        ntst(o, v);
        ntst(o + 256, v);
        ntst(o + 32768, v);
        ntst(o + 32768 + 256, v);
      }
    }
  } else {
#pragma unroll
    for (int j = 0; j < 8; j++) {
      const int n = nb2 + j * 16;
      const f32x4 bq = *(const f32x4*)(jb.bias + n);
#pragma unroll
      for (int i = 0; i < 4; i++) {
        const int m = mb2 + i * 16;
        ntst(jb.out + (long)m * 256 + n, acc[i][j] + bq);
      }
    }
  }
}

extern "C" void kernel_launch(void* const* d_in, const int* in_sizes, int n_in,
                              void* d_out, int out_size, void* d_ws,
                              size_t ws_size, hipStream_t stream) {
  (void)in_sizes; (void)n_in; (void)out_size; (void)ws_size;
  const float* x1 = (const float*)d_in[0];
  const float* x2 = (const float*)d_in[1];
  float* out = (float*)d_out;

  uint16_t* x1p = (uint16_t*)d_ws;  // [2][130][130][256] = 8,652,800
  uint16_t* x2b = x1p + 8652800;    // [2][64][64][256]   = 2,097,152
  uint16_t* wf = x2b + 2097152;     // 16 x 65536 frag-major

  WArgs wa;
  wa.w1[0] = (const float*)d_in[2];   // q1_w
  wa.w1[1] = (const float*)d_in[4];   // q2_w
  wa.w1[2] = (const float*)d_in[6];   // ks1_w
  wa.w1[3] = (const float*)d_in[8];   // ks2_w
  wa.w1[4] = (const float*)d_in[10];  // kup_w
  wa.w1[5] = (const float*)d_in[12];  // v1_w
  wa.w1[6] = (const float*)d_in[14];  // v2_w
  wa.kdw = (const float*)d_in[16];    // kdown_w
  prep_transpose<<<3201, 256, 0, stream>>>(wa, x1, x2, wf, x1p, x2b);

  // d_out float offsets (tuple order):
  // q1:0 q2:8388608 k_up:10485760 k_self1:18874368 k_self2:27262976
  // k_down:29360128 v1:31457280 v2:39845888
  JobArgs ja;
  ja.j[0] = {x1p, wf + 7 * 65536, (const float*)d_in[17], out + 29360128L, 0,    3};  // kdown
  ja.j[1] = {x1p, wf + 0 * 65536, (const float*)d_in[3],  out + 0L,        256,  0};  // q1
  ja.j[2] = {x1p, wf + 2 * 65536, (const float*)d_in[7],  out + 18874368L, 512,  0};  // ks1
  ja.j[3] = {x1p, wf + 5 * 65536, (const float*)d_in[13], out + 31457280L, 768,  0};  // v1
  ja.j[4] = {x2b, wf + 4 * 65536, (const float*)d_in[11], out + 10485760L, 1024, 2};  // kup
  ja.j[5] = {x2b, wf + 1 * 65536, (const float*)d_in[5],  out + 8388608L,  1088, 1};  // q2
  ja.j[6] = {x2b, wf + 3 * 65536, (const float*)d_in[9],  out + 27262976L, 1152, 1};  // ks2
  ja.j[7] = {x2b, wf + 6 * 65536, (const float*)d_in[15], out + 39845888L, 1216, 1};  // v2
  fused_gemm<<<1280, 256, 0, stream>>>(ja);
}